// Round 9
// baseline (358.391 us; speedup 1.0000x reference)
//
#include <hip/hip_runtime.h>
#include <hip/hip_fp16.h>
#include <math.h>

#define NH     16
#define HD     64
#define S_LEN  2048
#define THD_   1024
// exp(s*0.125) = exp2(s * 0.125 * log2(e))
#define SCALE_LOG2E 0.18033688011112042f

typedef __fp16 f16x8 __attribute__((ext_vector_type(8)));
typedef __fp16 f16x4 __attribute__((ext_vector_type(4)));
typedef __fp16 f16x2 __attribute__((ext_vector_type(2)));
typedef float  f32x4 __attribute__((ext_vector_type(4)));

#define GLOBAL_AS __attribute__((address_space(1)))
#define LDS_AS    __attribute__((address_space(3)))

// async global->LDS DMA, 16B per lane: LDS dest = base + lane*16 (HW rule),
// global src = per-lane address. [m97-proven path]
__device__ inline void dma16(const __half* g, __half* lds_base) {
  __builtin_amdgcn_global_load_lds((const GLOBAL_AS void*)g,
                                   (LDS_AS void*)lds_base, 16, 0, 0);
}

// ws layout (half-elements; total 41,943,040 B, proven safe):
//   region A @ 0        : q_h  8,388,608   [b][comp][h][s][hd]
//   region B @ 8388608  : k_h  8,388,608   same layout
//   region C @ 16777216 : vt_h 4,194,304   [b][h][hd][s]
// time-shared:
//   WqT fp16 @ B[0:2097152), WkT fp16 @ C[0:2097152)
//   rope tab fp32[2048][32][2] @ C[2097152:2359296)
//   WoT @ A[0:1048576), gn_h @ A[1048576:5242880)  (A dead after attn)

// ---------------------------------------------------------------------------
// Shared weight-transpose body: W[k][n] fp32 -> WT[n][k] fp16.
// ---------------------------------------------------------------------------
__device__ inline void wt_body(const float* __restrict__ W,
                               __half* __restrict__ WT, int id, int nmask,
                               int nshift) {
  int n = id & nmask;
  int k8 = (id >> nshift) * 8;
  int N = nmask + 1;
  f16x8 h;
#pragma unroll
  for (int j = 0; j < 8; ++j)
    h[j] = (__fp16)W[(size_t)(k8 + j) * N + n];
  *(f16x8*)(WT + (size_t)n * 1024 + k8) = h;
}

// ---------------------------------------------------------------------------
// Fused prep: blocks [0,1024) transpose Wq; [1024,2048) transpose Wk;
// [2048,2304) fill the RoPE cos/sin table tab[s][p] (2048 x 32).
// ---------------------------------------------------------------------------
__global__ __launch_bounds__(256) void prep_kernel(
    const float* __restrict__ Wq, const float* __restrict__ Wk,
    __half* __restrict__ WqT, __half* __restrict__ WkT,
    float2* __restrict__ tab) {
  int bid = blockIdx.x;
  int t = threadIdx.x;
  if (bid < 1024) {
    wt_body(Wq, WqT, bid * 256 + t, 2047, 11);
  } else if (bid < 2048) {
    wt_body(Wk, WkT, (bid - 1024) * 256 + t, 2047, 11);
  } else {
    int id = (bid - 2048) * 256 + t;  // 65536
    int p = id & 31;
    int s = id >> 5;
    float inv = expf(-0.28782313662425574f * (float)p);
    float sn, cs;
    sincosf((float)s * inv, &sn, &cs);
    tab[id] = make_float2(cs, sn);
  }
}

// ---------------------------------------------------------------------------
// fp16 MFMA GEMM: C = A(4096 x 1024) * B(1024 x N). 128m x 64n tile, BK=64.
// 4 waves; wave w computes rows [w*32, w*32+32) x all 64 cols.
// MODE 0: A = x fp32 (cast in staging), B = WT fp16; fused-RoPE epilogue
// MODE 2: A = x fp32, B = raw Wv fp32 column gather; scatter to vt
// MODE 3: A = gn_h fp16, B = WoT fp16; fp32 row-major to d_out
// ---------------------------------------------------------------------------
template <int MODE>
__global__ __launch_bounds__(256) void mfma_gemm(const void* __restrict__ Ap,
                                                 const void* __restrict__ Bp,
                                                 void* __restrict__ Cp,
                                                 const float2* __restrict__ tab) {
  __shared__ __fp16 As[128][72];
  __shared__ __fp16 Bs[64][72];
  const int t = threadIdx.x;
  const int w = t >> 6, lane = t & 63;
  const int quad = lane >> 4, lqi = lane & 15;
  const int wm = w * 32;
  const int n0 = blockIdx.x * 64, m0 = blockIdx.y * 128;

  f32x4 acc[2][4];
#pragma unroll
  for (int mt = 0; mt < 2; ++mt)
#pragma unroll
    for (int nt = 0; nt < 4; ++nt) acc[mt][nt] = (f32x4){0.f, 0.f, 0.f, 0.f};

  const int srow = t >> 3;         // staging row base (0..31)
  const int sc8 = (t & 7) * 8;     // staging col (halves)
  const int gn_ = t & 63;          // gather: n within tile
  const int gk0 = (t >> 6) * 8;    // gather: k base (0,8,16,24)

  for (int k0 = 0; k0 < 1024; k0 += 64) {
    if (k0) __syncthreads();
    // ---- A staging ----
    if (MODE == 3) {
      const __half* A16 = (const __half*)Ap;
#pragma unroll
      for (int p = 0; p < 4; ++p) {
        int row = srow + 32 * p;
        *(f16x8*)&As[row][sc8] =
            *(const f16x8*)(A16 + (size_t)(m0 + row) * 1024 + k0 + sc8);
      }
    } else {
      const float* A32 = (const float*)Ap;
#pragma unroll
      for (int p = 0; p < 4; ++p) {
        int row = srow + 32 * p;
        const float* src = A32 + (size_t)(m0 + row) * 1024 + k0 + sc8;
        float4 u = *(const float4*)src;
        float4 v = *(const float4*)(src + 4);
        f16x8 h;
        h[0] = (__fp16)u.x; h[1] = (__fp16)u.y;
        h[2] = (__fp16)u.z; h[3] = (__fp16)u.w;
        h[4] = (__fp16)v.x; h[5] = (__fp16)v.y;
        h[6] = (__fp16)v.z; h[7] = (__fp16)v.w;
        *(f16x8*)&As[row][sc8] = h;
      }
    }
    // ---- B staging ----
    if (MODE == 2) {
      const float* B32 = (const float*)Bp;  // Wv row-major [k][1024]
#pragma unroll
      for (int p = 0; p < 2; ++p) {
        int kc = gk0 + 32 * p;
        f16x8 h;
#pragma unroll
        for (int j = 0; j < 8; ++j)
          h[j] = (__fp16)B32[(size_t)(k0 + kc + j) * 1024 + n0 + gn_];
        *(f16x8*)&Bs[gn_][kc] = h;
      }
    } else {
      const __half* B16 = (const __half*)Bp;  // WT [n][k]
      if (srow < 32) {
#pragma unroll
        for (int p = 0; p < 2; ++p) {
          int row = srow + 32 * p;
          *(f16x8*)&Bs[row][sc8] =
              *(const f16x8*)(B16 + (size_t)(n0 + row) * 1024 + k0 + sc8);
        }
      }
    }
    __syncthreads();
    // ---- MFMA ----
#pragma unroll
    for (int ks = 0; ks < 2; ++ks) {
      f16x8 af[2], bf[4];
#pragma unroll
      for (int mt = 0; mt < 2; ++mt)
        af[mt] = *(const f16x8*)&As[wm + mt * 16 + lqi][ks * 32 + quad * 8];
#pragma unroll
      for (int nt = 0; nt < 4; ++nt)
        bf[nt] = *(const f16x8*)&Bs[nt * 16 + lqi][ks * 32 + quad * 8];
#pragma unroll
      for (int mt = 0; mt < 2; ++mt)
#pragma unroll
        for (int nt = 0; nt < 4; ++nt)
          acc[mt][nt] = __builtin_amdgcn_mfma_f32_16x16x32_f16(
              af[mt], bf[nt], acc[mt][nt], 0, 0, 0);
    }
  }

  // ---- epilogue ----
  const int b = m0 >> 11;
  const int s0 = (m0 & 2047) + wm + quad * 4;
  if (MODE == 0) {
    __half* dst = (__half*)Cp;
    const int comp = n0 >> 10, hh = (n0 >> 6) & 15;
    __half* base = dst + ((size_t)(b * 2 + comp) * NH + hh) * (size_t)S_LEN * HD;
#pragma unroll
    for (int nt = 0; nt < 2; ++nt) {
      int p = nt * 16 + lqi;
#pragma unroll
      for (int mt = 0; mt < 2; ++mt) {
#pragma unroll
        for (int i = 0; i < 4; ++i) {
          int s = s0 + mt * 16 + i;
          float2 cs = tab[s * 32 + p];
          float x1 = acc[mt][nt][i], x2 = acc[mt][nt + 2][i];
          base[(size_t)s * HD + p] = __float2half(x1 * cs.x - x2 * cs.y);
          base[(size_t)s * HD + p + 32] = __float2half(x2 * cs.x + x1 * cs.y);
        }
      }
    }
  } else if (MODE == 2) {
    __half* vt = (__half*)Cp;
    const int hh = n0 >> 6;
#pragma unroll
    for (int nt = 0; nt < 4; ++nt) {
      int hd = nt * 16 + lqi;
      __half* base = vt + (((size_t)b * NH + hh) * HD + hd) * S_LEN;
#pragma unroll
      for (int mt = 0; mt < 2; ++mt) {
        f16x4 hv;
#pragma unroll
        for (int i = 0; i < 4; ++i) hv[i] = (__fp16)acc[mt][nt][i];
        *(f16x4*)(base + s0 + mt * 16) = hv;
      }
    }
  } else {
    float* Co = (float*)Cp;
#pragma unroll
    for (int mt = 0; mt < 2; ++mt)
#pragma unroll
      for (int i = 0; i < 4; ++i) {
        int m = m0 + wm + mt * 16 + quad * 4 + i;
#pragma unroll
        for (int nt = 0; nt < 4; ++nt)
          Co[(size_t)m * 1024 + n0 + nt * 16 + lqi] = acc[mt][nt][i];
      }
  }
}

// ---------------------------------------------------------------------------
// Differential attention. R8 restructure targeting the LDS pipe (R7 math:
// ~648 LDS-cyc/wave/kt -> ~69 us of LDS-unit time in a 109 us kernel):
//  * K staged via async global_load_lds (width 16) into a DOUBLE-BUFFERED
//    fragment-ordered LDS region -> staging ds_writes gone, ONE barrier/kt
//    (compiler's vmcnt(0)-before-barrier doubles as DMA completion wait).
//  * V read straight into registers per wave (4-way redundancy hits L1),
//    removing 8 b128 LDS reads/wave/kt and making room for the K dbuf.
// LDS: Kbuf 2x16KB + P 36.9KB = 69.6 KB -> 2 blocks/CU.
// ---------------------------------------------------------------------------
__global__ __launch_bounds__(256, 2) void attn_kernel(
    const __half* __restrict__ q_h, const __half* __restrict__ k_h,
    const __half* __restrict__ vt_h, float* __restrict__ out,
    const float* __restrict__ lq1, const float* __restrict__ lk1,
    const float* __restrict__ lq2, const float* __restrict__ lk2,
    const float* __restrict__ lam_init_p) {
  // K chunks: c = str*8 + mt*2 + ks, 1 KB each, [buf][c][lane*16B]
  __shared__ __half Kbuf[2][16][512];
  __shared__ __half P_lds[4][2][32][72];  // wave-private P

  const int t = threadIdx.x;
  const int w = t >> 6, lane = t & 63;
  const int quad = lane >> 4, lqi = lane & 15;
  const int qt = blockIdx.x;   // 0..15 (128-query tiles)
  const int bh = blockIdx.y;   // 0..31
  const int b = bh >> 4, h = bh & 15;

  const size_t c1 = ((size_t)(b * 2 + 0) * NH + h) * (size_t)S_LEN * HD;
  const size_t c2 = ((size_t)(b * 2 + 1) * NH + h) * (size_t)S_LEN * HD;
  const size_t vtb = ((size_t)b * NH + h) * (size_t)HD * S_LEN;
  const int q0 = qt * 128 + w * 32;

  f16x8 qf[2][2][2];  // [stream][nt][ks]
#pragma unroll
  for (int nt = 0; nt < 2; ++nt)
#pragma unroll
    for (int ks = 0; ks < 2; ++ks) {
      size_t a = (size_t)(q0 + nt * 16 + lqi) * HD + ks * 32 + quad * 8;
      qf[0][nt][ks] = *(const f16x8*)(q_h + c1 + a);
      qf[1][nt][ks] = *(const f16x8*)(q_h + c2 + a);
    }

  f32x4 O[2][4][2];
#pragma unroll
  for (int s = 0; s < 2; ++s)
#pragma unroll
    for (int mt = 0; mt < 4; ++mt)
#pragma unroll
      for (int nt = 0; nt < 2; ++nt) O[s][mt][nt] = (f32x4){0.f, 0.f, 0.f, 0.f};
  float lsum[2][2] = {{0.f, 0.f}, {0.f, 0.f}};

  // K DMA: wave w owns chunks c = w + ci*4, ci in [0,4)
  auto k_src = [&](int c, int k0) -> const __half* {
    int str = c >> 3, mt = (c >> 1) & 3, ks = c & 1;
    return k_h + (str ? c2 : c1) + (size_t)(k0 + mt * 16 + lqi) * HD +
           ks * 32 + quad * 8;
  };

  // prologue: DMA tile 0 into buf 0
#pragma unroll
  for (int ci = 0; ci < 4; ++ci) {
    int c = w + ci * 4;
    dma16(k_src(c, 0), &Kbuf[0][c][0]);
  }

  for (int kt = 0; kt < 32; ++kt) {
    const int k0 = kt * 64;
    const int cur = kt & 1;
    // drains this wave's outstanding DMAs (compiler emits vmcnt(0) before
    // s_barrier) and syncs all waves -> Kbuf[cur] complete & visible; also
    // guarantees everyone finished reading Kbuf[cur^1] (their kt-1 tile).
    __syncthreads();
    if (kt < 31) {
#pragma unroll
      for (int ci = 0; ci < 4; ++ci) {
        int c = w + ci * 4;
        dma16(k_src(c, k0 + 64), &Kbuf[cur ^ 1][c][0]);
      }
    }
    // V fragments straight to registers (consumed ~800 cyc later in PV)
    f16x8 vf[2][4];
#pragma unroll
    for (int ks2 = 0; ks2 < 2; ++ks2)
#pragma unroll
      for (int mt = 0; mt < 4; ++mt)
        vf[ks2][mt] = *(const f16x8*)(vt_h + vtb +
                                      (size_t)(mt * 16 + lqi) * S_LEN + k0 +
                                      ks2 * 32 + quad * 8);

    // ---- scores + exp + P store ----
#pragma unroll
    for (int mt = 0; mt < 4; ++mt) {
#pragma unroll
      for (int str = 0; str < 2; ++str) {
        f16x8 kf0 = *(const f16x8*)&Kbuf[cur][str * 8 + mt * 2 + 0][lane * 8];
        f16x8 kf1 = *(const f16x8*)&Kbuf[cur][str * 8 + mt * 2 + 1][lane * 8];
#pragma unroll
        for (int nt = 0; nt < 2; ++nt) {
          f32x4 s = (f32x4){0.f, 0.f, 0.f, 0.f};
          s = __builtin_amdgcn_mfma_f32_16x16x32_f16(kf0, qf[str][nt][0], s,
                                                     0, 0, 0);
          s = __builtin_amdgcn_mfma_f32_16x16x32_f16(kf1, qf[str][nt][1], s,
                                                     0, 0, 0);
          float e0 = __builtin_amdgcn_exp2f(s[0] * SCALE_LOG2E);
          float e1 = __builtin_amdgcn_exp2f(s[1] * SCALE_LOG2E);
          float e2 = __builtin_amdgcn_exp2f(s[2] * SCALE_LOG2E);
          float e3 = __builtin_amdgcn_exp2f(s[3] * SCALE_LOG2E);
          lsum[str][nt] += (e0 + e1) + (e2 + e3);
          union { f16x4 v; f16x2 h2[2]; } pu;
          pu.h2[0] = __builtin_amdgcn_cvt_pkrtz(e0, e1);
          pu.h2[1] = __builtin_amdgcn_cvt_pkrtz(e2, e3);
          *(f16x4*)&P_lds[w][str][nt * 16 + lqi][mt * 16 + quad * 4] = pu.v;
        }
      }
    }
    // ---- PV (wave-private P round-trip; no barrier needed) ----
#pragma unroll
    for (int ks2 = 0; ks2 < 2; ++ks2) {
      f16x8 pf[2][2];
#pragma unroll
      for (int str = 0; str < 2; ++str)
#pragma unroll
        for (int nt = 0; nt < 2; ++nt)
          pf[str][nt] = *(const f16x8*)&P_lds[w][str][nt * 16 + lqi]
                                             [ks2 * 32 + quad * 8];
#pragma unroll
      for (int mt = 0; mt < 4; ++mt) {
#pragma unroll
        for (int str = 0; str < 2; ++str)
#pragma unroll
          for (int nt = 0; nt < 2; ++nt)
            O[str][mt][nt] = __builtin_amdgcn_mfma_f32_16x16x32_f16(
                vf[ks2][mt], pf[str][nt], O[str][mt][nt], 0, 0, 0);
      }
    }
  }

  const float lam0 = lam_init_p[0];
  const float lam = expf(lq1[h] * lk1[h]) - expf(lq2[h] * lk2[h]) + lam0;
#pragma unroll
  for (int str = 0; str < 2; ++str)
#pragma unroll
    for (int nt = 0; nt < 2; ++nt) {
      float v = lsum[str][nt];
      v += __shfl_xor(v, 16);
      v += __shfl_xor(v, 32);
      lsum[str][nt] = v;
    }
#pragma unroll
  for (int nt = 0; nt < 2; ++nt) {
    float il1 = 1.f / lsum[0][nt];
    float il2 = lam / lsum[1][nt];
    int q = q0 + nt * 16 + lqi;
#pragma unroll
    for (int mt = 0; mt < 4; ++mt) {
      f32x4 o;
#pragma unroll
      for (int i = 0; i < 4; ++i)
        o[i] = O[0][mt][nt][i] * il1 - O[1][mt][nt][i] * il2;
      *(f32x4*)(out + ((size_t)(b * S_LEN + q)) * THD_ + h * HD + mt * 16 +
                quad * 4) = o;
    }
  }
}

// ---------------------------------------------------------------------------
// Fused GroupNorm + Wo transpose.
// ---------------------------------------------------------------------------
__global__ __launch_bounds__(256) void gn_wt_kernel(
    const float* __restrict__ src, __half* __restrict__ dst,
    const float* __restrict__ gw, const float* __restrict__ gb,
    const float* __restrict__ lam_init_p, const float* __restrict__ Wo,
    __half* __restrict__ WoT) {
  if (blockIdx.x >= 16384) {
    wt_body(Wo, WoT, (blockIdx.x - 16384) * 256 + threadIdx.x, 1023, 10);
    return;
  }
  int g = blockIdx.x * 4 + (threadIdx.x >> 6);
  int lane = threadIdx.x & 63;
  float v = src[(size_t)g * 64 + lane];
  float s = v, sq = v * v;
#pragma unroll
  for (int off = 32; off; off >>= 1) {
    s += __shfl_xor(s, off);
    sq += __shfl_xor(sq, off);
  }
  float mean = s * (1.f / 64.f);
  float var = sq * (1.f / 64.f) - mean * mean;
  float rs = rsqrtf(var + 1e-5f);
  int h = g & 15;
  float w = gw[h * 64 + lane], bb = gb[h * 64 + lane];
  dst[(size_t)g * 64 + lane] =
      __float2half(((v - mean) * rs * w + bb) * (1.f - lam_init_p[0]));
}

// ---------------------------------------------------------------------------
extern "C" void kernel_launch(void* const* d_in, const int* in_sizes, int n_in,
                              void* d_out, int out_size, void* d_ws,
                              size_t ws_size, hipStream_t stream) {
  const float* x = (const float*)d_in[0];
  const float* Wq = (const float*)d_in[1];
  const float* Wk = (const float*)d_in[2];
  const float* Wv = (const float*)d_in[3];
  const float* Wo = (const float*)d_in[4];
  const float* lq1 = (const float*)d_in[5];
  const float* lk1 = (const float*)d_in[6];
  const float* lq2 = (const float*)d_in[7];
  const float* lk2 = (const float*)d_in[8];
  const float* lam_init = (const float*)d_in[9];
  const float* gnw = (const float*)d_in[10];
  const float* gnb = (const float*)d_in[11];
  float* out = (float*)d_out;

  __half* q_h = (__half*)d_ws;          // region A
  __half* k_h = q_h + 8388608;          // region B
  __half* vt_h = k_h + 8388608;         // region C
  __half* WqT = k_h;                    // B[0:2097152)  (dead after q-GEMM)
  __half* WkT = vt_h;                   // C[0:2097152)  (dead after k-GEMM)
  float2* tab = (float2*)(vt_h + 2097152);  // C[2097152:2359296) fp32 pairs
  __half* WoT = q_h;                    // A[0:1048576)  (q dead after attn)
  __half* gn_h = q_h + 1048576;         // A[1048576:5242880)

  dim3 blk(256);
  // fused prep: Wq/Wk transposes + rope table
  prep_kernel<<<2304, blk, 0, stream>>>(Wq, Wk, WqT, WkT, tab);
  // projections (MFMA, fused table-RoPE for q/k); 128m x 64n tiles
  mfma_gemm<0><<<dim3(32, 32), blk, 0, stream>>>(x, WqT, q_h, tab);
  mfma_gemm<0><<<dim3(32, 32), blk, 0, stream>>>(x, WkT, k_h, tab);
  mfma_gemm<2><<<dim3(16, 32), blk, 0, stream>>>(x, Wv, vt_h, nullptr);
  // differential attention -> d_out (DMA-staged dbuf K, register V)
  attn_kernel<<<dim3(16, 32), blk, 0, stream>>>(q_h, k_h, vt_h, out, lq1, lk1,
                                                lq2, lk2, lam_init);
  // fused GroupNorm + Wo transpose
  gn_wt_kernel<<<16896, blk, 0, stream>>>(out, gn_h, gnw, gnb, lam_init, Wo,
                                          WoT);
  // output projection: gn_h @ WoT -> d_out
  mfma_gemm<3><<<dim3(16, 32), blk, 0, stream>>>(gn_h, WoT, out, nullptr);
}